// Round 10
// baseline (189.138 us; speedup 1.0000x reference)
//
#include <hip/hip_runtime.h>

#define B_SZ 16384
#define D_SZ 256
#define C_SZ 2000
#define C_PAD 2048
#define MARGIN_F 1.0f
#define GBLK 4096

typedef __bf16 bf16x8 __attribute__((ext_vector_type(8)));
typedef float floatx16 __attribute__((ext_vector_type(16)));

__device__ inline void gld_lds16(const void* g, void* l) {
  __builtin_amdgcn_global_load_lds(
      (const __attribute__((address_space(1))) void*)g,
      (__attribute__((address_space(3))) void*)l, 16, 0, 0);
}

// Frag-major layout for mfma_f32_32x32x16_bf16 (verified R3/R6-R9):
//   chunk(tile32, ks, lane) -> 8 bf16 at base + ((tile*16 + ks)*64 + lane)*8
//   lane holds M[tile*32 + (lane&31)][ks*16 + (lane>>5)*8 + j], j=0..7

// ---- prep: blocks 0..511 pred->predf + gt; blocks 512..575 sig->sigf ----
// gt[b] = fp32 dot of bf16-rounded pred[b] and bf16-rounded sig[:,label_b];
// GEMM epilogue uses this gt so the label column's hinge == MARGIN + O(1e-3);
// final reduce subtracts B_SZ*MARGIN. No mask, no corr (validated R9).
__global__ __launch_bounds__(256) void prep_kernel(
    const float* __restrict__ pred, const float* __restrict__ sig,
    const int* __restrict__ label, __bf16* __restrict__ predf,
    __bf16* __restrict__ sigf, float* __restrict__ gt,
    float* __restrict__ accs, unsigned int* __restrict__ cnt) {
  int bid = (int)blockIdx.x;
  int tid = threadIdx.x;
  if (bid < 512) {
    __shared__ float ldsP[32][260];   // +4 pad: float4-aligned rows (1040 B)
    // phase A: coalesced tile load (32 rows x 256 cols fp32)
#pragma unroll
    for (int it = 0; it < 8; it++) {
      int idx = it * 1024 + tid * 4;
      int r = idx >> 8, c = idx & 255;
      float4 v = *(const float4*)(pred + (size_t)(bid * 32 + r) * D_SZ + c);
      *(float4*)&ldsP[r][c] = v;
    }
    __syncthreads();
    // phase B: frag-major predf, coalesced 16B/lane writes
#pragma unroll
    for (int it = 0; it < 4; it++) {
      int ch = it * 256 + tid;          // 0..1023
      int lane = ch & 63, ks = ch >> 6; // ks 0..15
      int r = lane & 31, kb = ks * 16 + (lane >> 5) * 8;
      float4 u0 = *(const float4*)&ldsP[r][kb];
      float4 u1 = *(const float4*)&ldsP[r][kb + 4];
      bf16x8 o;
      o[0] = (__bf16)u0.x; o[1] = (__bf16)u0.y; o[2] = (__bf16)u0.z; o[3] = (__bf16)u0.w;
      o[4] = (__bf16)u1.x; o[5] = (__bf16)u1.y; o[6] = (__bf16)u1.z; o[7] = (__bf16)u1.w;
      *(bf16x8*)(predf + ((size_t)(bid * 16 + ks) * 64 + lane) * 8) = o;
    }
    // phase C: bf16-consistent gt; 4 waves x 8 rows
    int lane = tid & 63, w = tid >> 6;
    for (int rr = 0; rr < 8; rr++) {
      int r = w * 8 + rr;
      int row = bid * 32 + r;
      int lbl = label[row];
      float4 pq = *(const float4*)&ldsP[r][lane * 4];
      float pv[4] = {pq.x, pq.y, pq.z, pq.w};
      float s = 0.f;
#pragma unroll
      for (int i = 0; i < 4; i++)
        s += (float)(__bf16)pv[i] * (float)(__bf16)sig[(size_t)(lane * 4 + i) * C_SZ + lbl];
#pragma unroll
      for (int off = 32; off > 0; off >>= 1) s += __shfl_down(s, off, 64);
      if (lane == 0) gt[row] = s;
    }
  } else {
    if (bid == 512 && tid < 65) {
      if (tid < 64) accs[tid] = 0.f; else *cnt = 0u;
    }
    int ct = bid - 512;                 // coltile 0..63
#pragma unroll
    for (int it = 0; it < 4; it++) {
      int ch = it * 256 + tid;
      int lane = ch & 63, ks = ch >> 6;
      int col = ct * 32 + (lane & 31);
      int kb = ks * 16 + (lane >> 5) * 8;
      bf16x8 o;
      if (col < C_SZ) {
#pragma unroll
        for (int j = 0; j < 8; j++) o[j] = (__bf16)sig[(size_t)(kb + j) * C_SZ + col];
      } else {
#pragma unroll
        for (int j = 0; j < 8; j++) o[j] = (__bf16)0.f;
      }
      *(bf16x8*)(sigf + ((size_t)(ct * 16 + ks) * 64 + lane) * 8) = o;
    }
  }
}

// ---- GEMM + hinge + last-block reduce ----
// block = 64 rows x 128 cols; A (full-K, 32 KB) in LDS; B frags (1 coltile
// full-K = 64 VGPR) in registers per wave; acc 32 VGPR. One barrier, one
// MFMA pass (32 MFMA + 32 conflict-free ds_read_b128 per wave).
// launch_bounds(256,3): ~130 VGPR -> 3 waves/SIMD; LDS 32 KB -> 3 blocks/CU
// (12 waves/CU, 2x R6 TLP). Grid 4096: XCD-major rsb -> per-XCD predf slice
// (1 MB) + sigf (1 MB) stay L2-resident.
__global__ __launch_bounds__(256, 3) void mfma_fused_kernel(
    const __bf16* __restrict__ predf, const __bf16* __restrict__ sigf,
    const float* __restrict__ gt, float* __restrict__ accs,
    unsigned int* __restrict__ cnt, float* __restrict__ out) {
  __shared__ __bf16 As[2048 * 8];   // 32 KB: [rt*16+ks][lane][8]
  __shared__ float gtS[64];
  __shared__ float red[4];
  __shared__ unsigned int lastFlag;
  int tid = threadIdx.x;
  int lane = tid & 63;
  int w = tid >> 6;
  int kh = lane >> 5, lm = lane & 31;
  int bid = (int)blockIdx.x;
  int rsb = (bid & 7) * 32 + ((bid >> 3) & 31);   // row-group 0..255 (64 rows)
  int cg = bid >> 8;                              // colgroup 0..15 (128 cols)

  // stage A: 2048 chunks of 16 B, straight frag-major copy (8 instr/wave)
#pragma unroll
  for (int t = 0; t < 8; t++) {
    int q0 = w * 512 + t * 64;
    gld_lds16(predf + ((size_t)rsb * 2048 + q0 + lane) * 8, (void*)(As + (size_t)q0 * 8));
  }
  if (tid < 64) gtS[tid] = gt[rsb * 64 + tid];

  // B fragments: coltile cg*4+w, full K, registers
  bf16x8 bfrg[16];
#pragma unroll
  for (int ks = 0; ks < 16; ks++)
    bfrg[ks] = *(const bf16x8*)(sigf + (((size_t)(cg * 4 + w) * 16 + ks) * 64 + lane) * 8);
  __syncthreads();

  floatx16 acc[2] = {};
#pragma unroll
  for (int ks = 0; ks < 16; ks++) {
#pragma unroll
    for (int rt = 0; rt < 2; rt++) {
      bf16x8 a = *(const bf16x8*)(As + (size_t)((rt * 16 + ks) * 64 + lane) * 8);
      acc[rt] = __builtin_amdgcn_mfma_f32_32x32x16_bf16(a, bfrg[ks], acc[rt], 0, 0, 0);
    }
  }

  // epilogue: C/D layout col=lane&31, row=(reg&3)+8*(reg>>2)+4*(lane>>5)
  int col = cg * 128 + w * 32 + lm;
  float keep = (col < C_SZ) ? 1.f : 0.f;
  float sum = 0.f;
#pragma unroll
  for (int rt = 0; rt < 2; rt++)
#pragma unroll
    for (int reg = 0; reg < 16; reg++) {
      int rl = rt * 32 + (reg & 3) + 8 * (reg >> 2) + 4 * kh;
      sum += keep * fmaxf(acc[rt][reg] + MARGIN_F - gtS[rl], 0.f);
    }
#pragma unroll
  for (int off = 32; off > 0; off >>= 1) sum += __shfl_down(sum, off, 64);
  if (lane == 0) red[w] = sum;
  __syncthreads();
  if (tid == 0) {
    atomicAdd(&accs[bid & 63], red[0] + red[1] + red[2] + red[3]);
    __threadfence();
    unsigned int old = atomicAdd(cnt, 1u);
    lastFlag = (old == GBLK - 1) ? 1u : 0u;
  }
  __syncthreads();
  if (lastFlag && tid < 64) {
    float s = atomicAdd(&accs[tid], 0.f);   // coherent cross-XCD read
#pragma unroll
    for (int off = 32; off > 0; off >>= 1) s += __shfl_down(s, off, 64);
    if (tid == 0) out[0] = s - (float)B_SZ * MARGIN_F;
  }
}

extern "C" void kernel_launch(void* const* d_in, const int* in_sizes, int n_in,
                              void* d_out, int out_size, void* d_ws, size_t ws_size,
                              hipStream_t stream) {
  const float* pred  = (const float*)d_in[0];   // (B, D) fp32
  const int*   label = (const int*)d_in[1];     // (B,)
  // d_in[2] = train_classes = arange(C), unused
  const float* sig   = (const float*)d_in[3];   // (D, C) fp32
  float* out = (float*)d_out;

  float*        gt    = (float*)d_ws;                                  // 64 KB
  float*        accs  = (float*)((char*)d_ws + (64 << 10));            // 256 B
  unsigned int* cnt   = (unsigned int*)((char*)d_ws + (66 << 10));     // 4 B
  __bf16*       predf = (__bf16*)((char*)d_ws + (128 << 10));          // 8 MB
  __bf16*       sigf  = (__bf16*)((char*)d_ws + (128 << 10) + (8 << 20)); // 1 MB

  prep_kernel<<<576, 256, 0, stream>>>(pred, sig, label, predf, sigf, gt, accs, cnt);
  mfma_fused_kernel<<<GBLK, 256, 0, stream>>>(predf, sigf, gt, accs, cnt, out);
}

// Round 11
// 104.350 us; speedup vs baseline: 1.8125x; 1.8125x over previous
//
#include <hip/hip_runtime.h>

#define B_SZ 16384
#define D_SZ 256
#define C_SZ 2000
#define C_PAD 2048
#define MARGIN_F 1.0f
#define NBLK 1024

typedef float floatx16 __attribute__((ext_vector_type(16)));

__device__ inline void gld_lds16(const void* g, void* l) {
  __builtin_amdgcn_global_load_lds(
      (const __attribute__((address_space(1))) void*)g,
      (__attribute__((address_space(3))) void*)l, 16, 0, 0);
}

// fp8 frag-major layout for v_mfma_f32_32x32x16_fp8_fp8 (A/B: 2 VGPR = 8 fp8):
//   chunk(tile32, ks, lane) -> 8 fp8 bytes at base + ((tile*16 + ks)*64 + lane)*8
//   lane holds M[tile*32 + (lane&31)][ks*16 + (lane>>5)*8 + j], j=0..7
// (same index pattern as the R3-verified bf16 32x32x16, elements now 1 B)

__device__ inline int2 pack8_fp8(const float* v) {
  int lo = __builtin_amdgcn_cvt_pk_fp8_f32(v[0], v[1], 0, false);
  lo = __builtin_amdgcn_cvt_pk_fp8_f32(v[2], v[3], lo, true);
  int hi = __builtin_amdgcn_cvt_pk_fp8_f32(v[4], v[5], 0, false);
  hi = __builtin_amdgcn_cvt_pk_fp8_f32(v[6], v[7], hi, true);
  return make_int2(lo, hi);
}
__device__ inline float rt_fp8(float x) {   // round-trip through fp8 e4m3
  int p = __builtin_amdgcn_cvt_pk_fp8_f32(x, x, 0, false);
  return __builtin_amdgcn_cvt_f32_fp8(p, 0);
}

// ---- prep: blocks 0..511 pred->predq + gt; blocks 512..575 sig->sigq ----
// gt[b] = fp32 dot of fp8-rounded pred[b] and fp8-rounded sig[:,label_b];
// GEMM epilogue uses this gt so the label column's hinge == MARGIN + eps;
// reduce subtracts B_SZ*MARGIN. No mask, no corr (algebra validated R9).
__global__ __launch_bounds__(256) void prep_kernel(
    const float* __restrict__ pred, const float* __restrict__ sig,
    const int* __restrict__ label, char* __restrict__ predq,
    char* __restrict__ sigq, float* __restrict__ gt) {
  int bid = (int)blockIdx.x;
  int tid = threadIdx.x;
  if (bid < 512) {
    __shared__ float ldsP[32][260];   // +4 pad: float4-aligned rows
    // phase A: coalesced tile load (32 rows x 256 K fp32)
#pragma unroll
    for (int it = 0; it < 8; it++) {
      int idx = it * 1024 + tid * 4;
      int r = idx >> 8, c = idx & 255;
      *(float4*)&ldsP[r][c] = *(const float4*)(pred + (size_t)(bid * 32 + r) * D_SZ + c);
    }
    __syncthreads();
    // phase B: frag-major predq, 8 B/lane coalesced writes
#pragma unroll
    for (int it = 0; it < 4; it++) {
      int ch = it * 256 + tid;          // 0..1023
      int lane = ch & 63, ks = ch >> 6; // ks 0..15
      int r = lane & 31, kb = ks * 16 + (lane >> 5) * 8;
      float v[8];
#pragma unroll
      for (int j = 0; j < 8; j++) v[j] = ldsP[r][kb + j];
      *(int2*)(predq + ((size_t)(bid * 16 + ks) * 64 + lane) * 8) = pack8_fp8(v);
    }
    // phase C: fp8-consistent gt; 4 waves x 8 rows
    int lane = tid & 63, w = tid >> 6;
    for (int rr = 0; rr < 8; rr++) {
      int r = w * 8 + rr;
      int row = bid * 32 + r;
      int lbl = label[row];
      float s = 0.f;
#pragma unroll
      for (int i = 0; i < 4; i++)
        s += rt_fp8(ldsP[r][lane * 4 + i]) *
             rt_fp8(sig[(size_t)(lane * 4 + i) * C_SZ + lbl]);
#pragma unroll
      for (int off = 32; off > 0; off >>= 1) s += __shfl_down(s, off, 64);
      if (lane == 0) gt[row] = s;
    }
  } else {
    int ct = bid - 512;                 // coltile 0..63
#pragma unroll
    for (int it = 0; it < 4; it++) {
      int ch = it * 256 + tid;
      int lane = ch & 63, ks = ch >> 6;
      int col = ct * 32 + (lane & 31);
      int kb = ks * 16 + (lane >> 5) * 8;
      float v[8];
#pragma unroll
      for (int j = 0; j < 8; j++)
        v[j] = (col < C_SZ) ? sig[(size_t)(kb + j) * C_SZ + col] : 0.f;
      *(int2*)(sigq + ((size_t)(ct * 16 + ks) * 64 + lane) * 8) = pack8_fp8(v);
    }
  }
}

// ---- GEMM + hinge (fp8): B-tile in LDS once (32 KB), full-K A in regs ----
// block = 256 rows x 128 cols, 4 waves; wave = 64 rows (2 rowtiles) x 128.
// afr[2][16] = 64 VGPR (half of bf16) -> no spill pressure; 32 KB LDS ->
// 3 blocks/CU (12 waves/CU). Per coltile: 16 ds_read_b64 + 32 MFMA
// (256 LDS-bytes/MFMA, well under the 128 B/cyc LDS wall).
// Partial to partial[bid]; NO completion counter (R10 lesson: 53 us serial).
__global__ __launch_bounds__(256) void mfma_fused_kernel(
    const char* __restrict__ predq, const char* __restrict__ sigq,
    const float* __restrict__ gt, float* __restrict__ partial) {
  __shared__ char Bs[4096 * 8];   // 32 KB: 4 coltiles x 16 ks x 64 lanes x 8 B
  __shared__ float red[4];
  int tid = threadIdx.x;
  int lane = tid & 63;
  int w = tid >> 6;
  int kh = lane >> 5, lm = lane & 31;
  int bid = (int)blockIdx.x;
  int i = bid >> 3;
  int rsb = (bid & 7) * 8 + (i & 7);   // row superblock 0..63 (256 rows)
  int cg = i >> 3;                     // colgroup 0..15 (128 cols)

  // stage B tile (128 cols x 256 K fp8 = 32 KB), straight frag-major copy
#pragma unroll
  for (int s = 0; s < 8; s++) {
    int q0 = s * 256 + w * 64;         // 16B chunk id, 0..2047
    gld_lds16(sigq + ((size_t)cg * 2048 + q0 + lane) * 16, (void*)(Bs + (size_t)q0 * 16));
  }

  // A frags: full K for 2 rowtiles (rows rsb*256 + w*64 .. +63), 64 VGPR
  long afr[2][16];
#pragma unroll
  for (int rt = 0; rt < 2; rt++)
#pragma unroll
    for (int ks = 0; ks < 16; ks++)
      afr[rt][ks] = *(const long*)(predq +
          (((size_t)(rsb * 8 + w * 2 + rt) * 16 + ks) * 64 + lane) * 8);

  // mg = margin - gt for the rows this lane owns (C/D row map, verified R3)
  float mgv[2][16];
#pragma unroll
  for (int rt = 0; rt < 2; rt++)
#pragma unroll
    for (int reg = 0; reg < 16; reg++) {
      int row = rsb * 256 + w * 64 + rt * 32 + (reg & 3) + 8 * (reg >> 2) + 4 * kh;
      mgv[rt][reg] = MARGIN_F - gt[row];
    }
  __syncthreads();

  float sum = 0.f;
#pragma unroll
  for (int ct = 0; ct < 4; ct++) {
    floatx16 acc0 = {}, acc1 = {};
#pragma unroll
    for (int ks = 0; ks < 16; ks++) {
      long b = *(const long*)(Bs + (size_t)((ct * 16 + ks) * 64 + lane) * 8);
      acc0 = __builtin_amdgcn_mfma_f32_32x32x16_fp8_fp8(afr[0][ks], b, acc0, 0, 0, 0);
      acc1 = __builtin_amdgcn_mfma_f32_32x32x16_fp8_fp8(afr[1][ks], b, acc1, 0, 0, 0);
    }
    int col = cg * 128 + ct * 32 + lm;
    float keep = (col < C_SZ) ? 1.f : 0.f;   // padded cols: s=0 but hinge!=0
#pragma unroll
    for (int reg = 0; reg < 16; reg++) {
      sum += keep * fmaxf(acc0[reg] + mgv[0][reg], 0.f);
      sum += keep * fmaxf(acc1[reg] + mgv[1][reg], 0.f);
    }
  }
#pragma unroll
  for (int off = 32; off > 0; off >>= 1) sum += __shfl_down(sum, off, 64);
  if (lane == 0) red[w] = sum;
  __syncthreads();
  if (tid == 0) partial[bid] = red[0] + red[1] + red[2] + red[3];
}

// ---- final reduce: out = sum(partial) - B*MARGIN; single block ----
__global__ __launch_bounds__(256) void reduce_kernel(
    const float* __restrict__ partial, float* __restrict__ out) {
  int tid = threadIdx.x;
  float s = 0.f;
  for (int i = tid * 4; i < NBLK; i += 1024) {
    float4 p = *(const float4*)(partial + i);
    s += p.x + p.y + p.z + p.w;
  }
#pragma unroll
  for (int off = 32; off > 0; off >>= 1) s += __shfl_down(s, off, 64);
  __shared__ float red[4];
  if ((tid & 63) == 0) red[tid >> 6] = s;
  __syncthreads();
  if (tid == 0) out[0] = red[0] + red[1] + red[2] + red[3] - (float)B_SZ * MARGIN_F;
}

extern "C" void kernel_launch(void* const* d_in, const int* in_sizes, int n_in,
                              void* d_out, int out_size, void* d_ws, size_t ws_size,
                              hipStream_t stream) {
  const float* pred  = (const float*)d_in[0];   // (B, D) fp32
  const int*   label = (const int*)d_in[1];     // (B,)
  // d_in[2] = train_classes = arange(C), unused
  const float* sig   = (const float*)d_in[3];   // (D, C) fp32
  float* out = (float*)d_out;

  float* gt      = (float*)d_ws;                                   // 64 KB
  float* partial = (float*)((char*)d_ws + (64 << 10));             // 4 KB
  char*  predq   = (char*)d_ws + (128 << 10);                      // 4 MB
  char*  sigq    = (char*)d_ws + (128 << 10) + (4 << 20);          // 512 KB

  prep_kernel<<<576, 256, 0, stream>>>(pred, sig, label, predq, sigq, gt);
  mfma_fused_kernel<<<NBLK, 256, 0, stream>>>(predq, sigq, gt, partial);
  reduce_kernel<<<1, 256, 0, stream>>>(partial, out);
}